// Round 1
// baseline (273.836 us; speedup 1.0000x reference)
//
#include <hip/hip_runtime.h>
#include <math.h>

#define NB 2
#define NCH 192
#define NH 48
#define NW 48
#define NL 2304
#define NK 4
#define NN 16
#define NR 12
#define ND 44
#define NDP 48      // padded d
#define NCHUNK 36
#define CLEN 64     // NL / NCHUNK

// workspace float offsets
#define SZ_XT    (NB * NCH * NL)                 // 884736
#define SZ_XDBL  (NB * NK * NL * NDP)            // 884736
#define SZ_DELTA (NB * NK * NL * NCH)            // 3538944
#define SZ_YBUF  (NB * NK * NCH * NL)            // 3538944
#define SZ_P     (NB * NK * NCHUNK * NCH * NN)   // 884736

// ---------------------------------------------------------------- transpose x
__global__ __launch_bounds__(256) void k_transpose(const float* __restrict__ x,
                                                   float* __restrict__ xT) {
    int bc = blockIdx.x;                       // b*192 + c
    const float* src = x + (size_t)bc * NL;
    float* dst = xT + (size_t)bc * NL;
    __shared__ float tile[NW * (NH + 1)];      // tile[w*49+h]
    for (int i = threadIdx.x; i < NL; i += 256) {
        int h = i / NW, w = i % NW;
        tile[w * 49 + h] = src[i];
    }
    __syncthreads();
    for (int i = threadIdx.x; i < NL; i += 256) {
        dst[i] = tile[i + i / NH];             // i = w*48+h -> w*49+h
    }
}

// ------------------------------------------------- x_dbl = einsum(xs, x_proj)
// out layout: xdbl[bk][l][48]  (d: 0..11 dts, 12..27 B, 28..43 C, 44..47 pad)
__global__ __launch_bounds__(192) void k_proj(const float* __restrict__ x,
                                              const float* __restrict__ xT,
                                              const float* __restrict__ xpw,
                                              float* __restrict__ xdbl) {
    int bid = blockIdx.x;                      // 8 * 36
    int bk = bid / 36;
    int lt0 = (bid % 36) * 64;
    int b = bk >> 2, k = bk & 3;
    int tid = threadIdx.x;
    int lt = tid & 15;                         // l sub tile
    int dt = tid >> 4;                         // 0..11
    __shared__ float WT[NCH * NDP];            // [c][d] 36.9KB
    __shared__ float XS[48 * 64];              // 12.3KB
    for (int i = tid; i < NCH * NDP; i += 192) {
        int c = i / NDP, d = i % NDP;
        WT[i] = (d < ND) ? xpw[((size_t)k * ND + d) * NCH + c] : 0.0f;
    }
    const float* bx = ((k & 1) ? xT : x) + (size_t)b * NCH * NL;
    bool rev = (k >= 2);
    float acc[16];
#pragma unroll
    for (int i = 0; i < 16; ++i) acc[i] = 0.0f;
    for (int ch = 0; ch < 4; ++ch) {
        int c0 = ch * 48;
        __syncthreads();
        for (int i = tid; i < 48 * 64; i += 192) {
            int cc = i >> 6, j = i & 63;
            int gl = lt0 + j;
            if (rev) gl = NL - 1 - gl;
            XS[i] = bx[(size_t)(c0 + cc) * NL + gl];
        }
        __syncthreads();
#pragma unroll 4
        for (int cc = 0; cc < 48; ++cc) {
            float4 wv = *(const float4*)&WT[(c0 + cc) * NDP + dt * 4];
            float4 xv = *(const float4*)&XS[cc * 64 + lt * 4];
            float xa[4] = {xv.x, xv.y, xv.z, xv.w};
            float wa[4] = {wv.x, wv.y, wv.z, wv.w};
#pragma unroll
            for (int li = 0; li < 4; ++li)
#pragma unroll
                for (int di = 0; di < 4; ++di)
                    acc[li * 4 + di] = fmaf(xa[li], wa[di], acc[li * 4 + di]);
        }
    }
    if (dt < 11) {                             // skip pad rows 44..47
#pragma unroll
        for (int li = 0; li < 4; ++li) {
            int l = lt0 + lt * 4 + li;
            float4 o = make_float4(acc[li * 4 + 0], acc[li * 4 + 1],
                                   acc[li * 4 + 2], acc[li * 4 + 3]);
            *(float4*)&xdbl[((size_t)bk * NL + l) * NDP + dt * 4] = o;
        }
    }
}

// -------------------------------- delta = softplus(dt_proj @ xdbl[:12] + bias)
// out layout: delta[bk][l][c]
__global__ __launch_bounds__(192) void k_delta(const float* __restrict__ xdbl,
                                               const float* __restrict__ dtw,
                                               const float* __restrict__ dt_bias,
                                               float* __restrict__ delta) {
    int bid = blockIdx.x;                      // 8 * 24
    int bk = bid / 24;
    int l0 = (bid % 24) * 96;
    int k = bk & 3;
    int c = threadIdx.x;                       // 0..191
    const float4* wp = (const float4*)(dtw + ((size_t)k * NCH + c) * NR);
    float4 w0 = wp[0], w1 = wp[1], w2 = wp[2];
    float bias = dt_bias[k * NCH + c];
    for (int i = 0; i < 96; ++i) {
        int l = l0 + i;
        const float4* xd = (const float4*)(xdbl + ((size_t)bk * NL + l) * NDP);
        float4 a0 = xd[0], a1 = xd[1], a2 = xd[2];
        float acc = bias;
        acc = fmaf(w0.x, a0.x, acc); acc = fmaf(w0.y, a0.y, acc);
        acc = fmaf(w0.z, a0.z, acc); acc = fmaf(w0.w, a0.w, acc);
        acc = fmaf(w1.x, a1.x, acc); acc = fmaf(w1.y, a1.y, acc);
        acc = fmaf(w1.z, a1.z, acc); acc = fmaf(w1.w, a1.w, acc);
        acc = fmaf(w2.x, a2.x, acc); acc = fmaf(w2.y, a2.y, acc);
        acc = fmaf(w2.z, a2.z, acc); acc = fmaf(w2.w, a2.w, acc);
        // stable softplus = max(x,0) + log1p(exp(-|x|))
        float sp = fmaxf(acc, 0.0f) + log1pf(expf(-fabsf(acc)));
        delta[((size_t)bk * NL + l) * NCH + c] = sp;
    }
}

// ---------------------------------------------------- scan pass 1 (per-chunk)
__global__ __launch_bounds__(192) void k_s1(const float* __restrict__ x,
                                            const float* __restrict__ xT,
                                            const float* __restrict__ xdbl,
                                            const float* __restrict__ delta,
                                            const float* __restrict__ A_logs,
                                            float* __restrict__ Pbuf,
                                            float* __restrict__ Hend) {
    int bid = blockIdx.x;                      // 8 * NCHUNK
    int bk = bid / NCHUNK;
    int ch = bid % NCHUNK;
    int b = bk >> 2, k = bk & 3;
    int c = threadIdx.x;
    float A2[NN];
    {
        const float4* ap = (const float4*)(A_logs + ((size_t)(k * NCH + c)) * NN);
        float4 a0 = ap[0], a1 = ap[1], a2 = ap[2], a3 = ap[3];
        float t[16] = {a0.x, a0.y, a0.z, a0.w, a1.x, a1.y, a1.z, a1.w,
                       a2.x, a2.y, a2.z, a2.w, a3.x, a3.y, a3.z, a3.w};
#pragma unroll
        for (int n = 0; n < NN; ++n) A2[n] = -expf(t[n]) * 1.44269504f;
    }
    float h[NN];
#pragma unroll
    for (int n = 0; n < NN; ++n) h[n] = 0.0f;
    float S = 0.0f;
    const float* dp = delta + (size_t)bk * NL * NCH + c;
    const float* up = ((k & 1) ? xT : x) + ((size_t)b * NCH + c) * NL;
    int l0 = ch * CLEN;
    for (int i = 0; i < CLEN; ++i) {
        int l = l0 + i;
        float dlt = dp[(size_t)l * NCH];
        int ui = (k >= 2) ? (NL - 1 - l) : l;
        float uv = up[ui];
        float du = dlt * uv;
        S += dlt;
        const float4* br = (const float4*)(xdbl + ((size_t)bk * NL + l) * NDP + NR);
        float4 b0 = br[0], b1 = br[1], b2 = br[2], b3 = br[3];
        float Bv[16] = {b0.x, b0.y, b0.z, b0.w, b1.x, b1.y, b1.z, b1.w,
                        b2.x, b2.y, b2.z, b2.w, b3.x, b3.y, b3.z, b3.w};
#pragma unroll
        for (int n = 0; n < NN; ++n) {
            float dA = exp2f(dlt * A2[n]);
            h[n] = fmaf(dA, h[n], du * Bv[n]);
        }
    }
    size_t ob = (((size_t)bk * NCHUNK + ch) * NCH + c) * NN;
#pragma unroll
    for (int q = 0; q < 4; ++q) {
        float4 hv = make_float4(h[q * 4], h[q * 4 + 1], h[q * 4 + 2], h[q * 4 + 3]);
        *(float4*)&Hend[ob + q * 4] = hv;
        float4 pv = make_float4(exp2f(S * A2[q * 4 + 0]), exp2f(S * A2[q * 4 + 1]),
                                exp2f(S * A2[q * 4 + 2]), exp2f(S * A2[q * 4 + 3]));
        *(float4*)&Pbuf[ob + q * 4] = pv;
    }
}

// ------------------------------------------------ scan pass 2 (chunk prefix)
__global__ __launch_bounds__(256) void k_s2(const float* __restrict__ Pbuf,
                                            const float* __restrict__ Hend,
                                            float* __restrict__ Hin) {
    int g = blockIdx.x * 256 + threadIdx.x;    // 0..24575
    int bk = g / (NCH * NN);
    int cn = g % (NCH * NN);
    float h = 0.0f;
    for (int j = 0; j < NCHUNK; ++j) {
        size_t idx = ((size_t)bk * NCHUNK + j) * (NCH * NN) + cn;
        Hin[idx] = h;
        h = fmaf(Pbuf[idx], h, Hend[idx]);
    }
}

// ---------------------------------------------------- scan pass 3 (emit y)
__global__ __launch_bounds__(192) void k_s3(const float* __restrict__ x,
                                            const float* __restrict__ xT,
                                            const float* __restrict__ xdbl,
                                            const float* __restrict__ delta,
                                            const float* __restrict__ A_logs,
                                            const float* __restrict__ Ds,
                                            const float* __restrict__ Hin,
                                            float* __restrict__ ybuf) {
    int bid = blockIdx.x;
    int bk = bid / NCHUNK;
    int ch = bid % NCHUNK;
    int b = bk >> 2, k = bk & 3;
    int c = threadIdx.x;
    float A2[NN];
    {
        const float4* ap = (const float4*)(A_logs + ((size_t)(k * NCH + c)) * NN);
        float4 a0 = ap[0], a1 = ap[1], a2 = ap[2], a3 = ap[3];
        float t[16] = {a0.x, a0.y, a0.z, a0.w, a1.x, a1.y, a1.z, a1.w,
                       a2.x, a2.y, a2.z, a2.w, a3.x, a3.y, a3.z, a3.w};
#pragma unroll
        for (int n = 0; n < NN; ++n) A2[n] = -expf(t[n]) * 1.44269504f;
    }
    float h[NN];
    size_t ob = (((size_t)bk * NCHUNK + ch) * NCH + c) * NN;
    {
        const float4* hp = (const float4*)(Hin + ob);
        float4 h0 = hp[0], h1 = hp[1], h2 = hp[2], h3 = hp[3];
        float t[16] = {h0.x, h0.y, h0.z, h0.w, h1.x, h1.y, h1.z, h1.w,
                       h2.x, h2.y, h2.z, h2.w, h3.x, h3.y, h3.z, h3.w};
#pragma unroll
        for (int n = 0; n < NN; ++n) h[n] = t[n];
    }
    float dval = Ds[k * NCH + c];
    const float* dp = delta + (size_t)bk * NL * NCH + c;
    const float* up = ((k & 1) ? xT : x) + ((size_t)b * NCH + c) * NL;
    float* yp = ybuf + ((size_t)bk * NCH + c) * NL;
    int l0 = ch * CLEN;
    for (int i = 0; i < CLEN; ++i) {
        int l = l0 + i;
        float dlt = dp[(size_t)l * NCH];
        int ui = (k >= 2) ? (NL - 1 - l) : l;
        float uv = up[ui];
        float du = dlt * uv;
        const float* row = xdbl + ((size_t)bk * NL + l) * NDP;
        const float4* br = (const float4*)(row + NR);
        float4 b0 = br[0], b1 = br[1], b2 = br[2], b3 = br[3];
        float Bv[16] = {b0.x, b0.y, b0.z, b0.w, b1.x, b1.y, b1.z, b1.w,
                        b2.x, b2.y, b2.z, b2.w, b3.x, b3.y, b3.z, b3.w};
        const float4* cr = (const float4*)(row + NR + NN);
        float4 c0 = cr[0], c1 = cr[1], c2 = cr[2], c3 = cr[3];
        float Cv[16] = {c0.x, c0.y, c0.z, c0.w, c1.x, c1.y, c1.z, c1.w,
                        c2.x, c2.y, c2.z, c2.w, c3.x, c3.y, c3.z, c3.w};
        float y = 0.0f;
#pragma unroll
        for (int n = 0; n < NN; ++n) {
            float dA = exp2f(dlt * A2[n]);
            h[n] = fmaf(dA, h[n], du * Bv[n]);
            y = fmaf(h[n], Cv[n], y);
        }
        y = fmaf(dval, uv, y);
        yp[l] = y;
    }
}

// ---------------------------------------------------------------- cross-merge
__global__ __launch_bounds__(256) void k_merge(const float* __restrict__ ybuf,
                                               float* __restrict__ out) {
    int bc = blockIdx.x;                       // b*192 + c
    int b = bc / NCH, c = bc % NCH;
    const float* y0 = ybuf + (((size_t)(b * NK + 0) * NCH) + c) * NL;
    const float* y1 = ybuf + (((size_t)(b * NK + 1) * NCH) + c) * NL;
    const float* y2 = ybuf + (((size_t)(b * NK + 2) * NCH) + c) * NL;
    const float* y3 = ybuf + (((size_t)(b * NK + 3) * NCH) + c) * NL;
    __shared__ float tile[NW * (NH + 1)];      // tile[w*49+h] = ym1[w*48+h]
    for (int i = threadIdx.x; i < NL; i += 256) {
        tile[i + i / NH] = y1[i] + y3[NL - 1 - i];
    }
    __syncthreads();
    float* op = out + (size_t)bc * NL;
    for (int i = threadIdx.x; i < NL; i += 256) {
        int h = i / NW, w = i % NW;
        op[i] = y0[i] + y2[NL - 1 - i] + tile[w * 49 + h];
    }
}

extern "C" void kernel_launch(void* const* d_in, const int* in_sizes, int n_in,
                              void* d_out, int out_size, void* d_ws, size_t ws_size,
                              hipStream_t stream) {
    const float* x      = (const float*)d_in[0];
    const float* xpw    = (const float*)d_in[1];
    const float* dtw    = (const float*)d_in[2];
    const float* A_logs = (const float*)d_in[3];
    const float* Ds     = (const float*)d_in[4];
    const float* dtb    = (const float*)d_in[5];
    float* out = (float*)d_out;

    float* ws = (float*)d_ws;
    float* xT    = ws;
    float* xdbl  = xT + SZ_XT;
    float* delta = xdbl + SZ_XDBL;
    float* ybuf  = delta + SZ_DELTA;
    float* Pbuf  = ybuf + SZ_YBUF;
    float* Hend  = Pbuf + SZ_P;
    float* Hin   = Hend + SZ_P;

    k_transpose<<<NB * NCH, 256, 0, stream>>>(x, xT);
    k_proj<<<NB * NK * 36, 192, 0, stream>>>(x, xT, xpw, xdbl);
    k_delta<<<NB * NK * 24, 192, 0, stream>>>(xdbl, dtw, dtb, delta);
    k_s1<<<NB * NK * NCHUNK, 192, 0, stream>>>(x, xT, xdbl, delta, A_logs, Pbuf, Hend);
    k_s2<<<(NB * NK * NCH * NN) / 256, 256, 0, stream>>>(Pbuf, Hend, Hin);
    k_s3<<<NB * NK * NCHUNK, 192, 0, stream>>>(x, xT, xdbl, delta, A_logs, Ds, Hin, ybuf);
    k_merge<<<NB * NCH, 256, 0, stream>>>(ybuf, out);
}

// Round 2
// 212.929 us; speedup vs baseline: 1.2860x; 1.2860x over previous
//
#include <hip/hip_runtime.h>
#include <math.h>

#define NB 2
#define NCH 192
#define NH 48
#define NW 48
#define NL 2304
#define NK 4
#define NN 16
#define NR 12
#define ND 44
#define NDP 48      // padded d
#define NCHUNK 96
#define CLEN 24     // NL / NCHUNK

// workspace float sizes
#define SZ_XT    (NB * NCH * NL)                 // 884736
#define SZ_UT0   (NB * NL * NCH)                 // 884736
#define SZ_XDBL  (NB * NK * NL * NDP)            // 884736
#define SZ_DELTA (NB * NK * NL * NCH)            // 3538944
#define SZ_YBUF  (NB * NK * NL * NCH)            // 3538944
#define SZ_P     (NB * NK * NCHUNK * NCH * NN)   // 2359296

// ------------------------------------------------- xT[b][c][w*48+h] (for proj)
__global__ __launch_bounds__(256) void k_transpose(const float* __restrict__ x,
                                                   float* __restrict__ xT) {
    int bc = blockIdx.x;                       // b*192 + c
    const float* src = x + (size_t)bc * NL;
    float* dst = xT + (size_t)bc * NL;
    __shared__ float tile[NW * (NH + 1)];      // tile[w*49+h]
    for (int i = threadIdx.x; i < NL; i += 256) {
        int h = i / NW, w = i % NW;
        tile[w * 49 + h] = src[i];
    }
    __syncthreads();
    for (int i = threadIdx.x; i < NL; i += 256) {
        dst[i] = tile[i + i / NH];             // i = w*48+h -> w*49+h
    }
}

// ------------------------------------------------- ut0[b][l][c] = x[b][c][l]
__global__ __launch_bounds__(256) void k_ut0(const float* __restrict__ x,
                                             float* __restrict__ ut0) {
    int b = blockIdx.x >> 5;                   // 2 b * 36 ltiles -> use /36
    int lt = blockIdx.x;                       // decode below
    b = lt / 36; lt = lt % 36;
    int l0 = lt * 64;
    __shared__ float tile[64 * 193];           // tile[j*193+c]
    const float* bx = x + (size_t)b * NCH * NL;
    for (int i = threadIdx.x; i < NCH * 64; i += 256) {
        int c = i >> 6, j = i & 63;            // lanes: j fast -> coalesced read
        tile[j * 193 + c] = bx[(size_t)c * NL + l0 + j];
    }
    __syncthreads();
    float* bo = ut0 + (size_t)b * NL * NCH;
    for (int i = threadIdx.x; i < NCH * 64; i += 256) {
        int j = i / NCH, c = i % NCH;          // lanes: c fast -> coalesced write
        bo[(size_t)(l0 + j) * NCH + c] = tile[j * 193 + c];
    }
}

// ------------------------------------------------- x_dbl = einsum(xs, x_proj)
// out layout: xdbl[bk][l][48]  (d: 0..11 dts, 12..27 B, 28..43 C, 44..47 pad)
__global__ __launch_bounds__(192) void k_proj(const float* __restrict__ x,
                                              const float* __restrict__ xT,
                                              const float* __restrict__ xpw,
                                              float* __restrict__ xdbl) {
    int bid = blockIdx.x;                      // 8 * 36
    int bk = bid / 36;
    int lt0 = (bid % 36) * 64;
    int b = bk >> 2, k = bk & 3;
    int tid = threadIdx.x;
    int lt = tid & 15;                         // l sub tile
    int dt = tid >> 4;                         // 0..11
    __shared__ float WT[NCH * NDP];            // [c][d] 36.9KB
    __shared__ float XS[48 * 64];              // 12.3KB
    for (int i = tid; i < NCH * NDP; i += 192) {
        int c = i / NDP, d = i % NDP;
        WT[i] = (d < ND) ? xpw[((size_t)k * ND + d) * NCH + c] : 0.0f;
    }
    const float* bx = ((k & 1) ? xT : x) + (size_t)b * NCH * NL;
    bool rev = (k >= 2);
    float acc[16];
#pragma unroll
    for (int i = 0; i < 16; ++i) acc[i] = 0.0f;
    for (int ch = 0; ch < 4; ++ch) {
        int c0 = ch * 48;
        __syncthreads();
        for (int i = tid; i < 48 * 64; i += 192) {
            int cc = i >> 6, j = i & 63;
            int gl = lt0 + j;
            if (rev) gl = NL - 1 - gl;
            XS[i] = bx[(size_t)(c0 + cc) * NL + gl];
        }
        __syncthreads();
#pragma unroll 4
        for (int cc = 0; cc < 48; ++cc) {
            float4 wv = *(const float4*)&WT[(c0 + cc) * NDP + dt * 4];
            float4 xv = *(const float4*)&XS[cc * 64 + lt * 4];
            float xa[4] = {xv.x, xv.y, xv.z, xv.w};
            float wa[4] = {wv.x, wv.y, wv.z, wv.w};
#pragma unroll
            for (int li = 0; li < 4; ++li)
#pragma unroll
                for (int di = 0; di < 4; ++di)
                    acc[li * 4 + di] = fmaf(xa[li], wa[di], acc[li * 4 + di]);
        }
    }
    if (dt < 11) {                             // skip pad rows 44..47
#pragma unroll
        for (int li = 0; li < 4; ++li) {
            int l = lt0 + lt * 4 + li;
            float4 o = make_float4(acc[li * 4 + 0], acc[li * 4 + 1],
                                   acc[li * 4 + 2], acc[li * 4 + 3]);
            *(float4*)&xdbl[((size_t)bk * NL + l) * NDP + dt * 4] = o;
        }
    }
}

// -------------------------------- delta = softplus(dt_proj @ xdbl[:12] + bias)
// out layout: delta[bk][l][c]
__global__ __launch_bounds__(192) void k_delta(const float* __restrict__ xdbl,
                                               const float* __restrict__ dtw,
                                               const float* __restrict__ dt_bias,
                                               float* __restrict__ delta) {
    int bid = blockIdx.x;                      // 8 * 48
    int bk = bid / 48;
    int l0 = (bid % 48) * 48;
    int k = bk & 3;
    int c = threadIdx.x;                       // 0..191
    const float4* wp = (const float4*)(dtw + ((size_t)k * NCH + c) * NR);
    float4 w0 = wp[0], w1 = wp[1], w2 = wp[2];
    float bias = dt_bias[k * NCH + c];
    for (int i = 0; i < 48; ++i) {
        int l = l0 + i;
        const float4* xd = (const float4*)(xdbl + ((size_t)bk * NL + l) * NDP);
        float4 a0 = xd[0], a1 = xd[1], a2 = xd[2];
        float acc = bias;
        acc = fmaf(w0.x, a0.x, acc); acc = fmaf(w0.y, a0.y, acc);
        acc = fmaf(w0.z, a0.z, acc); acc = fmaf(w0.w, a0.w, acc);
        acc = fmaf(w1.x, a1.x, acc); acc = fmaf(w1.y, a1.y, acc);
        acc = fmaf(w1.z, a1.z, acc); acc = fmaf(w1.w, a1.w, acc);
        acc = fmaf(w2.x, a2.x, acc); acc = fmaf(w2.y, a2.y, acc);
        acc = fmaf(w2.z, a2.z, acc); acc = fmaf(w2.w, a2.w, acc);
        float sp = fmaxf(acc, 0.0f) + log1pf(expf(-fabsf(acc)));
        delta[((size_t)bk * NL + l) * NCH + c] = sp;
    }
}

// u row index inside ut0 for direction k at scan position l (uniform scalar)
__device__ __forceinline__ int u_row(int k, int l) {
    int pos = (k >= 2) ? (NL - 1 - l) : l;
    if (k & 1) pos = (pos % 48) * 48 + (pos / 48);
    return pos;
}

// ---------------------------------------------------- scan pass 1 (per-chunk)
__global__ __launch_bounds__(192) void k_s1(const float* __restrict__ ut0,
                                            const float* __restrict__ xdbl,
                                            const float* __restrict__ delta,
                                            const float* __restrict__ A_logs,
                                            float* __restrict__ Pbuf,
                                            float* __restrict__ Hend) {
    int bid = blockIdx.x;                      // 8 * NCHUNK
    int bk = bid / NCHUNK;
    int ch = bid % NCHUNK;
    int b = bk >> 2, k = bk & 3;
    int c = threadIdx.x;
    float A2[NN];
    {
        const float4* ap = (const float4*)(A_logs + ((size_t)(k * NCH + c)) * NN);
        float4 a0 = ap[0], a1 = ap[1], a2 = ap[2], a3 = ap[3];
        float t[16] = {a0.x, a0.y, a0.z, a0.w, a1.x, a1.y, a1.z, a1.w,
                       a2.x, a2.y, a2.z, a2.w, a3.x, a3.y, a3.z, a3.w};
#pragma unroll
        for (int n = 0; n < NN; ++n) A2[n] = -expf(t[n]) * 1.44269504f;
    }
    float h[NN];
#pragma unroll
    for (int n = 0; n < NN; ++n) h[n] = 0.0f;
    float S = 0.0f;
    const float* dp = delta + (size_t)bk * NL * NCH + c;
    const float* up = ut0 + (size_t)b * NL * NCH + c;
    int l0 = ch * CLEN;
    for (int i = 0; i < CLEN; ++i) {
        int l = l0 + i;
        float dlt = dp[(size_t)l * NCH];
        float uv = up[(size_t)u_row(k, l) * NCH];
        float du = dlt * uv;
        S += dlt;
        const float4* br = (const float4*)(xdbl + ((size_t)bk * NL + l) * NDP + NR);
        float4 b0 = br[0], b1 = br[1], b2 = br[2], b3 = br[3];
        float Bv[16] = {b0.x, b0.y, b0.z, b0.w, b1.x, b1.y, b1.z, b1.w,
                        b2.x, b2.y, b2.z, b2.w, b3.x, b3.y, b3.z, b3.w};
#pragma unroll
        for (int n = 0; n < NN; ++n) {
            float dA = exp2f(dlt * A2[n]);
            h[n] = fmaf(dA, h[n], du * Bv[n]);
        }
    }
    size_t ob = (((size_t)bk * NCHUNK + ch) * NCH + c) * NN;
#pragma unroll
    for (int q = 0; q < 4; ++q) {
        float4 hv = make_float4(h[q * 4], h[q * 4 + 1], h[q * 4 + 2], h[q * 4 + 3]);
        *(float4*)&Hend[ob + q * 4] = hv;
        float4 pv = make_float4(exp2f(S * A2[q * 4 + 0]), exp2f(S * A2[q * 4 + 1]),
                                exp2f(S * A2[q * 4 + 2]), exp2f(S * A2[q * 4 + 3]));
        *(float4*)&Pbuf[ob + q * 4] = pv;
    }
}

// ------------------------------------------- scan pass 2 (chunk prefix, in place)
// After this kernel Hend[j] holds the INCOMING state for chunk j.
__global__ __launch_bounds__(256) void k_s2(const float* __restrict__ Pbuf,
                                            float* __restrict__ Hend) {
    int g = blockIdx.x * 256 + threadIdx.x;    // 0..24575
    int bk = g / (NCH * NN);
    int cn = g % (NCH * NN);
    float h = 0.0f;
    for (int j = 0; j < NCHUNK; ++j) {
        size_t idx = ((size_t)bk * NCHUNK + j) * (NCH * NN) + cn;
        float P = Pbuf[idx];
        float E = Hend[idx];
        Hend[idx] = h;
        h = fmaf(P, h, E);
    }
}

// ---------------------------------------------------- scan pass 3 (emit y)
// y stored as ybuf[bk][l][c] (coalesced)
__global__ __launch_bounds__(192) void k_s3(const float* __restrict__ ut0,
                                            const float* __restrict__ xdbl,
                                            const float* __restrict__ delta,
                                            const float* __restrict__ A_logs,
                                            const float* __restrict__ Ds,
                                            const float* __restrict__ Hin,
                                            float* __restrict__ ybuf) {
    int bid = blockIdx.x;
    int bk = bid / NCHUNK;
    int ch = bid % NCHUNK;
    int b = bk >> 2, k = bk & 3;
    int c = threadIdx.x;
    float A2[NN];
    {
        const float4* ap = (const float4*)(A_logs + ((size_t)(k * NCH + c)) * NN);
        float4 a0 = ap[0], a1 = ap[1], a2 = ap[2], a3 = ap[3];
        float t[16] = {a0.x, a0.y, a0.z, a0.w, a1.x, a1.y, a1.z, a1.w,
                       a2.x, a2.y, a2.z, a2.w, a3.x, a3.y, a3.z, a3.w};
#pragma unroll
        for (int n = 0; n < NN; ++n) A2[n] = -expf(t[n]) * 1.44269504f;
    }
    float h[NN];
    size_t ob = (((size_t)bk * NCHUNK + ch) * NCH + c) * NN;
    {
        const float4* hp = (const float4*)(Hin + ob);
        float4 h0 = hp[0], h1 = hp[1], h2 = hp[2], h3 = hp[3];
        float t[16] = {h0.x, h0.y, h0.z, h0.w, h1.x, h1.y, h1.z, h1.w,
                       h2.x, h2.y, h2.z, h2.w, h3.x, h3.y, h3.z, h3.w};
#pragma unroll
        for (int n = 0; n < NN; ++n) h[n] = t[n];
    }
    float dval = Ds[k * NCH + c];
    const float* dp = delta + (size_t)bk * NL * NCH + c;
    const float* up = ut0 + (size_t)b * NL * NCH + c;
    float* yp = ybuf + (size_t)bk * NL * NCH + c;
    int l0 = ch * CLEN;
    for (int i = 0; i < CLEN; ++i) {
        int l = l0 + i;
        float dlt = dp[(size_t)l * NCH];
        float uv = up[(size_t)u_row(k, l) * NCH];
        float du = dlt * uv;
        const float* row = xdbl + ((size_t)bk * NL + l) * NDP;
        const float4* br = (const float4*)(row + NR);
        float4 b0 = br[0], b1 = br[1], b2 = br[2], b3 = br[3];
        float Bv[16] = {b0.x, b0.y, b0.z, b0.w, b1.x, b1.y, b1.z, b1.w,
                        b2.x, b2.y, b2.z, b2.w, b3.x, b3.y, b3.z, b3.w};
        const float4* cr = (const float4*)(row + NR + NN);
        float4 c0 = cr[0], c1 = cr[1], c2 = cr[2], c3 = cr[3];
        float Cv[16] = {c0.x, c0.y, c0.z, c0.w, c1.x, c1.y, c1.z, c1.w,
                        c2.x, c2.y, c2.z, c2.w, c3.x, c3.y, c3.z, c3.w};
        float y = 0.0f;
#pragma unroll
        for (int n = 0; n < NN; ++n) {
            float dA = exp2f(dlt * A2[n]);
            h[n] = fmaf(dA, h[n], du * Bv[n]);
            y = fmaf(h[n], Cv[n], y);
        }
        y = fmaf(dval, uv, y);
        yp[(size_t)l * NCH] = y;
    }
}

// ------------------------------------------- cross-merge from [bk][l][c] layout
// out[b][c][h*48+w] = Y0[h*48+w] + Y2[NL-1-(h*48+w)] + Y1[w*48+h] + Y3[NL-1-(w*48+h)]
__global__ __launch_bounds__(256) void k_merge(const float* __restrict__ ybuf,
                                               float* __restrict__ out) {
    int b = blockIdx.x / NH;
    int hh = blockIdx.x % NH;
    __shared__ float tile[NW * 193];           // tile[w*193+c]
    const float* Y0 = ybuf + (size_t)(b * NK + 0) * NL * NCH;
    const float* Y1 = ybuf + (size_t)(b * NK + 1) * NL * NCH;
    const float* Y2 = ybuf + (size_t)(b * NK + 2) * NL * NCH;
    const float* Y3 = ybuf + (size_t)(b * NK + 3) * NL * NCH;
    for (int i = threadIdx.x; i < NW * NCH; i += 256) {
        int w = i / NCH, c = i % NCH;
        int hw = hh * NW + w;
        int wh = w * NH + hh;
        float v = Y0[(size_t)hw * NCH + c]
                + Y2[(size_t)(NL - 1 - hw) * NCH + c]
                + Y1[(size_t)wh * NCH + c]
                + Y3[(size_t)(NL - 1 - wh) * NCH + c];
        tile[w * 193 + c] = v;
    }
    __syncthreads();
    for (int i = threadIdx.x; i < NW * NCH; i += 256) {
        int c = i / NW, w = i % NW;
        out[((size_t)(b * NCH + c)) * NL + hh * NW + w] = tile[w * 193 + c];
    }
}

extern "C" void kernel_launch(void* const* d_in, const int* in_sizes, int n_in,
                              void* d_out, int out_size, void* d_ws, size_t ws_size,
                              hipStream_t stream) {
    const float* x      = (const float*)d_in[0];
    const float* xpw    = (const float*)d_in[1];
    const float* dtw    = (const float*)d_in[2];
    const float* A_logs = (const float*)d_in[3];
    const float* Ds     = (const float*)d_in[4];
    const float* dtb    = (const float*)d_in[5];
    float* out = (float*)d_out;

    float* ws = (float*)d_ws;
    float* xT    = ws;
    float* ut0   = xT + SZ_XT;
    float* xdbl  = ut0 + SZ_UT0;
    float* delta = xdbl + SZ_XDBL;
    float* ybuf  = delta + SZ_DELTA;
    float* Pbuf  = ybuf + SZ_YBUF;
    float* Hend  = Pbuf + SZ_P;    // after k_s2 holds Hin (in-place)

    k_transpose<<<NB * NCH, 256, 0, stream>>>(x, xT);
    k_ut0<<<NB * 36, 256, 0, stream>>>(x, ut0);
    k_proj<<<NB * NK * 36, 192, 0, stream>>>(x, xT, xpw, xdbl);
    k_delta<<<NB * NK * 48, 192, 0, stream>>>(xdbl, dtw, dtb, delta);
    k_s1<<<NB * NK * NCHUNK, 192, 0, stream>>>(ut0, xdbl, delta, A_logs, Pbuf, Hend);
    k_s2<<<(NB * NK * NCH * NN) / 256, 256, 0, stream>>>(Pbuf, Hend);
    k_s3<<<NB * NK * NCHUNK, 192, 0, stream>>>(ut0, xdbl, delta, A_logs, Ds, Hend, ybuf);
    k_merge<<<NB * NH, 256, 0, stream>>>(ybuf, out);
}